// Round 5
// baseline (25.953 us; speedup 1.0000x reference)
//
#include <hip/hip_runtime.h>

// Problem constants (from reference)
#define VV     32000
#define DD     4096
#define BB     2
#define LL     2048
#define TIMG   32
#define TREG   264   // 33 * 8

typedef float vfloat4 __attribute__((ext_vector_type(4)));

__device__ __forceinline__ const float* row_src(
    int t, int b,
    const float* __restrict__ weight,
    const float* __restrict__ img_tok,
    const float* __restrict__ reg_tok,
    const float* __restrict__ img_emb,
    const float* __restrict__ reg_emb)
{
    if (t < VV)            return weight  + (size_t)t * DD;
    if (t < VV + 2)        return img_tok + (size_t)(t - VV) * DD;
    if (t < VV + 4)        return reg_tok + (size_t)(t - VV - 2) * DD;
    if (t < VV + 4 + TIMG) return img_emb + ((size_t)b * TIMG + (t - VV - 4)) * DD;
    return reg_emb + ((size_t)b * TREG + (t - VV - 4 - TIMG)) * DD;
}

// Two rows per block: 2048 blocks x 256 threads. Each thread issues 8
// independent float4 loads (4 per row, rows independent) before any store —
// doubles per-thread MLP and halves block count vs the 1-row/block version,
// to test whether block ramp/drain + the id->row dependency chain is the
// remaining ~16% gap to the copy ceiling.
__global__ __launch_bounds__(256) void embed_gather2_kernel(
    const float* __restrict__ weight,      // [VV, DD]
    const float* __restrict__ img_tok,     // [2, DD]
    const float* __restrict__ reg_tok,     // [2, DD]
    const float* __restrict__ img_emb,     // [BB, TIMG, DD]
    const float* __restrict__ reg_emb,     // [BB, TREG, DD]
    const int*   __restrict__ text,        // [BB, LL]
    float*       __restrict__ out)         // [BB, LL, DD]
{
    const int r0 = blockIdx.x * 2;
    const int r1 = r0 + 1;
    const int t0 = text[r0];
    const int t1 = text[r1];

    const float* s0 = row_src(t0, r0 >> 11, weight, img_tok, reg_tok, img_emb, reg_emb);
    const float* s1 = row_src(t1, r1 >> 11, weight, img_tok, reg_tok, img_emb, reg_emb);

    const vfloat4* __restrict__ s40 = (const vfloat4*)s0;
    const vfloat4* __restrict__ s41 = (const vfloat4*)s1;
    vfloat4* __restrict__ d40 = (vfloat4*)(out + (size_t)r0 * DD);
    vfloat4* __restrict__ d41 = (vfloat4*)(out + (size_t)r1 * DD);

    const int tid = threadIdx.x;
    vfloat4 v[8];
#pragma unroll
    for (int i = 0; i < 4; ++i) v[i]     = s40[tid + i * 256];
#pragma unroll
    for (int i = 0; i < 4; ++i) v[4 + i] = s41[tid + i * 256];
#pragma unroll
    for (int i = 0; i < 4; ++i) d40[tid + i * 256] = v[i];
#pragma unroll
    for (int i = 0; i < 4; ++i) d41[tid + i * 256] = v[4 + i];
}

extern "C" void kernel_launch(void* const* d_in, const int* in_sizes, int n_in,
                              void* d_out, int out_size, void* d_ws, size_t ws_size,
                              hipStream_t stream) {
    const float* weight  = (const float*)d_in[0];
    const float* img_tok = (const float*)d_in[1];
    const float* reg_tok = (const float*)d_in[2];
    const float* img_emb = (const float*)d_in[3];
    const float* reg_emb = (const float*)d_in[4];
    const int*   text    = (const int*)d_in[5];
    float* out = (float*)d_out;

    const int n_blocks = (BB * LL) / 2;  // 2048
    embed_gather2_kernel<<<n_blocks, 256, 0, stream>>>(
        weight, img_tok, reg_tok, img_emb, reg_emb, text, out);
}